// Round 8
// baseline (378.232 us; speedup 1.0000x reference)
//
#include <hip/hip_runtime.h>
#include <cstdint>

#define D_MODEL 1024
#define D_INNER 2048
#define LSEQ    4096
#define BATCH   2
#define M_ROWS  (BATCH * LSEQ)   // 8192
#define CHUNK   128
#define NCHUNK  (LSEQ / CHUNK)   // 32

typedef unsigned short u16;
typedef __bf16 bf16x8 __attribute__((ext_vector_type(8)));
typedef float f32x4 __attribute__((ext_vector_type(4)));
typedef u16 u16x4 __attribute__((ext_vector_type(4)));

__device__ __forceinline__ u16 f2bf(float f) {
  union { float f; unsigned u; } x; x.f = f;
  unsigned u = x.u;
  unsigned r = (u + 0x7FFFu + ((u >> 16) & 1u)) >> 16;
  return (u16)r;
}
__device__ __forceinline__ float bf2f(u16 h) {
  union { unsigned u; float f; } x; x.u = ((unsigned)h) << 16;
  return x.f;
}
__device__ __forceinline__ float sigmoidf_(float v) { return 1.0f / (1.0f + expf(-v)); }
__device__ __forceinline__ float siluf_(float v)    { return v / (1.0f + expf(-v)); }

__device__ __forceinline__ void gl_lds16(const void* g, void* l) {
  __builtin_amdgcn_global_load_lds(
      (const __attribute__((address_space(1))) void*)g,
      (__attribute__((address_space(3))) void*)l, 16, 0, 0);
}

#define SBAR()   asm volatile("s_barrier" ::: "memory")
#define WAITV0() asm volatile("s_waitcnt vmcnt(0)" ::: "memory")
#define WAITV4() asm volatile("s_waitcnt vmcnt(4)" ::: "memory")
#define WAITL0() do { asm volatile("s_waitcnt lgkmcnt(0)" ::: "memory"); __builtin_amdgcn_sched_barrier(0); } while (0)

// ---------------- cast fp32 -> bf16 (vectorized) ----------------
__global__ void __launch_bounds__(256)
cast_bf16_kernel(const float* __restrict__ in, u16* __restrict__ out, int n4) {
  int i = blockIdx.x * 256 + threadIdx.x;
  if (i < n4) {
    float4 v = ((const float4*)in)[i];
    u16x4 o;
    o.x = f2bf(v.x); o.y = f2bf(v.y); o.z = f2bf(v.z); o.w = f2bf(v.w);
    ((u16x4*)out)[i] = o;
  }
}

// ---------------- LayerNorm -> bf16 ----------------
__global__ void __launch_bounds__(256)
ln_kernel(const float* __restrict__ x, const float* __restrict__ w,
          const float* __restrict__ b, u16* __restrict__ xn) {
  const int row = blockIdx.x;
  const int t = threadIdx.x;
  const float4 v = ((const float4*)(x + (size_t)row * D_MODEL))[t];
  float s  = v.x + v.y + v.z + v.w;
  float ss = v.x * v.x + v.y * v.y + v.z * v.z + v.w * v.w;
#pragma unroll
  for (int o = 32; o > 0; o >>= 1) {
    s  += __shfl_xor(s, o);
    ss += __shfl_xor(ss, o);
  }
  __shared__ float red[8];
  const int wid = t >> 6, lane = t & 63;
  if (lane == 0) { red[wid] = s; red[4 + wid] = ss; }
  __syncthreads();
  s  = red[0] + red[1] + red[2] + red[3];
  ss = red[4] + red[5] + red[6] + red[7];
  const float mu  = s * (1.0f / D_MODEL);
  const float var = ss * (1.0f / D_MODEL) - mu * mu;
  const float rs  = rsqrtf(var + 1e-5f);
  const float4 wv = ((const float4*)w)[t];
  const float4 bv = ((const float4*)b)[t];
  u16x4 o4;
  o4.x = f2bf((v.x - mu) * rs * wv.x + bv.x);
  o4.y = f2bf((v.y - mu) * rs * wv.y + bv.y);
  o4.z = f2bf((v.z - mu) * rs * wv.z + bv.z);
  o4.w = f2bf((v.w - mu) * rs * wv.w + bv.w);
  ((u16x4*)(xn + (size_t)row * D_MODEL))[t] = o4;
}

// ======== 256x256 BK=64 8-wave 8-phase GEMM (m201-class), C = A * B^T ========
// LDS = 8 half-tile slots of 16KB: A[parity][half] at parity*32K + half*16K;
// B same at +64K. Phase = {ds_reads; stage ONE half-tile; bar; lgkm0; 16 MFMA;
// bar}. Stage order: P8':A(t1)x2, P1:B0(t1), P2:B1(t1), P4:A(t2)x2, P5:B0(t2),
// P6:B1(t2). vmcnt(4) ONLY at P4/P8 (after stage issue, before barrier):
// proves loads issued 2-4.5 phases earlier; in-flight never < 4 (T4). Last
// iteration: P4 -> vmcnt(0), P8 stages nothing. Swizzle: global chunk
// (c ^ (row&7)) staged at slot c; reads XOR the same -> 0 bank conflicts
// (measured R2-R4). Wave grid 2Mx4N, wave tile 128x64, acc[8][4].
#define MFMA_BF16 __builtin_amdgcn_mfma_f32_16x16x32_bf16

template<int EPI>
__global__ void __launch_bounds__(512, 1)
gemm8p(const u16* __restrict__ A, const u16* __restrict__ Bm,
       int M, int N, int K,
       const float* __restrict__ ef, float* __restrict__ of,
       u16* __restrict__ ob0, u16* __restrict__ ob1) {
  __shared__ __align__(1024) char lds[131072];
  const int tid  = threadIdx.x;
  const int wid  = tid >> 6, lane = tid & 63;
  const int nbx  = N >> 8;
  const int nwg  = nbx * (M >> 8);
  const int bid  = blockIdx.x;
  const int cpx  = nwg >> 3;                      // nwg % 8 == 0 for our shapes
  const int swzb = (bid & 7) * cpx + (bid >> 3);  // XCD-aware swizzle
  const int bx   = swzb % nbx, by = swzb / nbx;
  const size_t m0 = (size_t)by << 8, n0 = (size_t)bx << 8;
  const int wr = wid >> 2, wc = wid & 3;          // 2x4 waves; wave tile 128x64
  const size_t rb = (size_t)K * 2;

  // ---- staging: thread T covers (row = T>>3, chunk = T&7) of a 64-row round;
  // global source chunk pre-swizzled by row&7; LDS dest linear (lane*16).
  const int strow = lane >> 3;
  const int stchk = (lane & 7) ^ strow;           // (row&7) == strow
  const char* gA = (const char*)A  + (m0 + (size_t)(wid * 8 + strow)) * rb + stchk * 16;
  const char* gB = (const char*)Bm + (n0 + (size_t)(wid * 8 + strow)) * rb + stchk * 16;
  const int sdw = wid * 1024;

  auto ST_A = [&](int t, int h) {
    char* d = lds + (t & 1) * 32768 + h * 16384 + sdw;
    const char* s = gA + (size_t)t * 128 + (size_t)(h * 128) * rb;
    gl_lds16(s, d);
    gl_lds16(s + 64 * rb, d + 8192);
  };
  auto ST_B = [&](int t, int h) {
    char* d = lds + 65536 + (t & 1) * 32768 + h * 16384 + sdw;
    const char* s = gB + (size_t)t * 128 + (size_t)(h * 128) * rb;
    gl_lds16(s, d);
    gl_lds16(s + 64 * rb, d + 8192);
  };

  // ---- fragment reads (swizzled): slot byte = row*128 + ((kk*4+q)^(row&7))<<4
  const int q = lane >> 4, r15 = lane & 15;
  const int kx0 = ((q ^ (r15 & 7)) << 4);
  const int kx1 = (((4 + q) ^ (r15 & 7)) << 4);
  const int arow = r15 * 128;                          // + mf*2048
  const int brow = ((wc & 1) * 64 + r15) * 128;        // + nf*2048
  const char* aE = lds + wr * 16384;                   // even-tile A slot
  const char* bE = lds + 65536 + (wc >> 1) * 16384;    // even-tile B slot
  const char* aO = aE + 32768;
  const char* bO = bE + 32768;

  bf16x8 af[8], bf[4];
  f32x4 acc[8][4] = {};

#define RD_A(kx, base)  _Pragma("unroll") \
    for (int mf = 0; mf < 8; ++mf) af[mf] = *(const bf16x8*)((base) + mf * 2048 + arow + (kx));
#define RD_B(kx, base)  _Pragma("unroll") \
    for (int nf = 0; nf < 4; ++nf) bf[nf] = *(const bf16x8*)((base) + nf * 2048 + brow + (kx));
#define MM_LO() do { __builtin_amdgcn_s_setprio(1); _Pragma("unroll") \
    for (int mf = 0; mf < 8; ++mf) { \
      acc[mf][0] = MFMA_BF16(af[mf], bf[0], acc[mf][0], 0, 0, 0); \
      acc[mf][1] = MFMA_BF16(af[mf], bf[1], acc[mf][1], 0, 0, 0); } \
    __builtin_amdgcn_s_setprio(0); } while (0)
#define MM_HI() do { __builtin_amdgcn_s_setprio(1); _Pragma("unroll") \
    for (int mf = 0; mf < 8; ++mf) { \
      acc[mf][2] = MFMA_BF16(af[mf], bf[2], acc[mf][2], 0, 0, 0); \
      acc[mf][3] = MFMA_BF16(af[mf], bf[3], acc[mf][3], 0, 0, 0); } \
    __builtin_amdgcn_s_setprio(0); } while (0)

  const int nk = K >> 6;           // K-tiles (even)
  const int nIter = nk >> 1;

  // ---- prologue: T0 all 4 halves + A(T1) both halves; prove T0 ----
  ST_A(0, 0); ST_A(0, 1); ST_B(0, 0); ST_B(0, 1);
  ST_A(1, 0); ST_A(1, 1);
  WAITV4();                        // proves T0's 8 loads; A(T1) in flight
  SBAR();

  for (int i = 0; i < nIter; ++i) {
    const int t1 = 2 * i + 1, t2 = 2 * i + 2, t3 = 2 * i + 3;
    const bool pf = (t2 < nk);

    // P1: reads kk0(even tile); stage B0(t1)
    RD_A(kx0, aE); RD_B(kx0, bE);
    ST_B(t1, 0);
    SBAR(); WAITL0();
    MM_LO();
    SBAR();

    // P2: stage B1(t1); MFMA kk0 n-hi
    ST_B(t1, 1);
    SBAR();
    MM_HI();
    SBAR();

    // P3: reads kk1(even); MFMA kk1 n-lo
    RD_A(kx1, aE); RD_B(kx1, bE);
    SBAR(); WAITL0();
    MM_LO();
    SBAR();

    // P4: stage A(t2) both halves; vmcnt; MFMA kk1 n-hi
    if (pf) { ST_A(t2, 0); ST_A(t2, 1); WAITV4(); } else { WAITV0(); }
    SBAR();
    MM_HI();
    SBAR();

    // P5: reads kk0(odd tile); stage B0(t2)
    RD_A(kx0, aO); RD_B(kx0, bO);
    if (pf) ST_B(t2, 0);
    SBAR(); WAITL0();
    MM_LO();
    SBAR();

    // P6: stage B1(t2); MFMA kk0 n-hi
    if (pf) ST_B(t2, 1);
    SBAR();
    MM_HI();
    SBAR();

    // P7: reads kk1(odd); MFMA kk1 n-lo
    RD_A(kx1, aO); RD_B(kx1, bO);
    SBAR(); WAITL0();
    MM_LO();
    SBAR();

    // P8: stage A(t3) both halves; vmcnt(4); MFMA kk1 n-hi
    if (pf) { ST_A(t3, 0); ST_A(t3, 1); WAITV4(); }
    SBAR();
    MM_HI();
    SBAR();
  }

#undef RD_A
#undef RD_B
#undef MM_LO
#undef MM_HI

  // ---------- epilogue (16x16 C layout: col=lane&15, row=(lane>>4)*4+r) ----
  const int c0 = lane & 15;
  const int r0 = (lane >> 4) << 2;
  const bool isz = (EPI == 0) && (n0 >= (size_t)D_INNER);
#pragma unroll
  for (int mf = 0; mf < 8; ++mf) {
#pragma unroll
    for (int nf = 0; nf < 4; ++nf) {
#pragma unroll
      for (int rg = 0; rg < 4; ++rg) {
        const size_t row = m0 + (size_t)(wr * 128 + mf * 16 + r0 + rg);
        const size_t col = n0 + (size_t)(wc * 64 + nf * 16 + c0);
        const float v = acc[mf][nf][rg];
        if (EPI == 0) {
          if (!isz) ob0[row * D_INNER + col] = f2bf(v);
          else      ob1[row * D_INNER + (col - D_INNER)] = f2bf(siluf_(v));
        } else if (EPI == 1) {
          ob0[row * (size_t)N + col] = f2bf(v);
        } else {
          of[row * (size_t)N + col] = v + ef[row * (size_t)N + col];
        }
      }
    }
  }
}

// ======== 128x128 BK=64 4-wave dbuf GEMM (for GEMM3, 2 blocks/CU) ========
template<int EPI>
__global__ void __launch_bounds__(256, 2)
gemm128(const u16* __restrict__ A, const u16* __restrict__ Bm,
        int M, int N, int K,
        const float* __restrict__ ef, float* __restrict__ of,
        u16* __restrict__ ob0, u16* __restrict__ ob1) {
  __shared__ __align__(1024) char lds[65536];
  const int tid  = threadIdx.x;
  const int wid  = tid >> 6, lane = tid & 63;
  const int nbx  = N >> 7;
  const int nwg  = nbx * (M >> 7);
  const int bid  = blockIdx.x;
  const int cpx  = nwg >> 3;
  const int swzb = (bid & 7) * cpx + (bid >> 3);
  const int bx   = swzb % nbx, by = swzb / nbx;
  const size_t m0 = (size_t)by << 7, n0 = (size_t)bx << 7;
  const int wr = wid >> 1, wc = wid & 1;
  const size_t rb = (size_t)K * 2;

  const int sslot = (((lane & 3) ^ ((lane >> 3) & 3)) << 4);
  const char* gA = (const char*)A  + (m0 + (size_t)(wid * 16 + (lane >> 2))) * rb + sslot;
  const char* gB = (const char*)Bm + (n0 + (size_t)(wid * 16 + (lane >> 2))) * rb + sslot;
  const int sd = wid * 1024;

  const int q = lane >> 4, r15 = lane & 15;
  const int xr = ((q ^ ((r15 >> 1) & 3)) << 4);
  const int aoff = (wr * 64 + r15) * 64 + xr;
  const int boff = (wc * 64 + r15) * 64 + xr;

  f32x4 acc[4][4] = {};
  const int nk = K >> 6;

  auto STG = [&](const char* g, char* ldsbase, int kk, int r0v, size_t kbv) {
    gl_lds16(g + kbv + kk * 64 + (size_t)r0v * rb, ldsbase + kk * 8192 + r0v * 64 + sd);
  };

  STG(gA, lds, 0, 0, 0); STG(gA, lds, 0, 64, 0);
  STG(gB, lds + 16384, 0, 0, 0); STG(gB, lds + 16384, 0, 64, 0);
  STG(gA, lds, 1, 0, 0); STG(gA, lds, 1, 64, 0);
  STG(gB, lds + 16384, 1, 0, 0); STG(gB, lds + 16384, 1, 64, 0);
  WAITV4();
  SBAR();

  size_t kb = 128;
  for (int t = 0; t < nk; ++t) {
    const int cur = t & 1;
    const char* Ac = lds + cur * 32768;
    const char* Bc = Ac + 16384;
    char* An = lds + ((cur ^ 1) * 32768);
    char* Bn = An + 16384;
    const bool pf = (t + 1 < nk);
    bf16x8 af[4], bfv[4];

    if (pf) {
      STG(gA, An, 0, 0, kb); STG(gA, An, 0, 64, kb);
      STG(gB, Bn, 0, 0, kb); STG(gB, Bn, 0, 64, kb);
    }
#pragma unroll
    for (int mi = 0; mi < 4; ++mi) af[mi] = *(const bf16x8*)(Ac + aoff + mi * 1024);
#pragma unroll
    for (int ni = 0; ni < 4; ++ni) bfv[ni] = *(const bf16x8*)(Bc + boff + ni * 1024);
    __builtin_amdgcn_s_setprio(1);
#pragma unroll
    for (int mi = 0; mi < 4; ++mi)
#pragma unroll
      for (int ni = 0; ni < 4; ++ni)
        acc[mi][ni] = MFMA_BF16(af[mi], bfv[ni], acc[mi][ni], 0, 0, 0);
    __builtin_amdgcn_s_setprio(0);
    if (pf) { WAITV4(); } else { WAITV0(); }
    SBAR();

    if (pf) {
      STG(gA, An, 1, 0, kb); STG(gA, An, 1, 64, kb);
      STG(gB, Bn, 1, 0, kb); STG(gB, Bn, 1, 64, kb);
    }
#pragma unroll
    for (int mi = 0; mi < 4; ++mi) af[mi] = *(const bf16x8*)(Ac + 8192 + aoff + mi * 1024);
#pragma unroll
    for (int ni = 0; ni < 4; ++ni) bfv[ni] = *(const bf16x8*)(Bc + 8192 + boff + ni * 1024);
    __builtin_amdgcn_s_setprio(1);
#pragma unroll
    for (int mi = 0; mi < 4; ++mi)
#pragma unroll
      for (int ni = 0; ni < 4; ++ni)
        acc[mi][ni] = MFMA_BF16(af[mi], bfv[ni], acc[mi][ni], 0, 0, 0);
    __builtin_amdgcn_s_setprio(0);
    if (pf) { WAITV4(); SBAR(); }
    kb += 128;
  }

  const int c0 = lane & 15;
  const int r0 = (lane >> 4) << 2;
  const bool isz = (EPI == 0) && (n0 >= (size_t)D_INNER);
#pragma unroll
  for (int mi = 0; mi < 4; ++mi) {
#pragma unroll
    for (int ni = 0; ni < 4; ++ni) {
#pragma unroll
      for (int rg = 0; rg < 4; ++rg) {
        const size_t row = m0 + (size_t)(wr * 64 + mi * 16 + r0 + rg);
        const size_t col = n0 + (size_t)(wc * 64 + ni * 16 + c0);
        const float v = acc[mi][ni][rg];
        if (EPI == 0) {
          if (!isz) ob0[row * D_INNER + col] = f2bf(v);
          else      ob1[row * D_INNER + (col - D_INNER)] = f2bf(siluf_(v));
        } else if (EPI == 1) {
          ob0[row * (size_t)N + col] = f2bf(v);
        } else {
          of[row * (size_t)N + col] = v + ef[row * (size_t)N + col];
        }
      }
    }
  }
}

// ---------------- causal depthwise conv (K=4) + SiLU ----------------
__global__ void __launch_bounds__(256)
conv_silu_kernel(const u16* __restrict__ xin, const float* __restrict__ cw,
                 const float* __restrict__ cb, u16* __restrict__ xc) {
  const int c   = blockIdx.x * 256 + threadIdx.x;
  const int l0  = blockIdx.y * 8;
  const int bat = blockIdx.z;
  const size_t base = ((size_t)bat * LSEQ) * D_INNER + c;
  const float w0 = cw[c * 4 + 0], w1 = cw[c * 4 + 1], w2 = cw[c * 4 + 2], w3 = cw[c * 4 + 3];
  const float bb = cb[c];
  float v[11];
#pragma unroll
  for (int i = 0; i < 11; ++i) {
    const int l = l0 - 3 + i;
    v[i] = (l >= 0) ? bf2f(xin[base + (size_t)l * D_INNER]) : 0.0f;
  }
#pragma unroll
  for (int r = 0; r < 8; ++r) {
    const float acc = bb + w0 * v[r] + w1 * v[r + 1] + w2 * v[r + 2] + w3 * v[r + 3];
    xc[base + (size_t)(l0 + r) * D_INNER] = f2bf(siluf_(acc));
  }
}

// ---------------- chunked scan: pass A (2 channels/thread) ----------------
__global__ void __launch_bounds__(256)
scan_a_kernel(const u16* __restrict__ g, const u16* __restrict__ xc,
              const float* __restrict__ gbias,
              float* __restrict__ cA, float* __restrict__ cB) {
  const int c   = (blockIdx.x * 256 + threadIdx.x) * 2;
  const int ch  = blockIdx.y;
  const int bat = blockIdx.z;
  const float bb0 = gbias[c], bb1 = gbias[c + 1];
  size_t idx = ((size_t)bat * LSEQ + (size_t)ch * CHUNK) * D_INNER + c;
  float pA0 = 1.0f, hB0 = 0.0f, pA1 = 1.0f, hB1 = 0.0f;
  for (int t = 0; t < CHUNK; ++t) {
    const ushort2 gg = *(const ushort2*)(g + idx);
    const ushort2 xx = *(const ushort2*)(xc + idx);
    const float a0 = sigmoidf_(bf2f(gg.x) + bb0);
    const float a1 = sigmoidf_(bf2f(gg.y) + bb1);
    pA0 *= a0; hB0 = a0 * hB0 + (1.0f - a0) * bf2f(xx.x);
    pA1 *= a1; hB1 = a1 * hB1 + (1.0f - a1) * bf2f(xx.y);
    idx += D_INNER;
  }
  const size_t o = ((size_t)bat * NCHUNK + ch) * D_INNER + c;
  *(float2*)(cA + o) = make_float2(pA0, pA1);
  *(float2*)(cB + o) = make_float2(hB0, hB1);
}

// ---------------- pass B: serial scan over chunk summaries ----------------
__global__ void __launch_bounds__(256)
scan_b_kernel(const float* __restrict__ cA, const float* __restrict__ cB,
              float* __restrict__ carry) {
  const int tid = blockIdx.x * 256 + threadIdx.x;  // BATCH*D_INNER = 4096
  const int bat = tid >> 11;
  const int c   = tid & (D_INNER - 1);
  float h = 0.0f;
  const size_t base = (size_t)bat * NCHUNK * D_INNER + c;
  for (int i = 0; i < NCHUNK; ++i) {
    const size_t o = base + (size_t)i * D_INNER;
    carry[o] = h;
    h = cA[o] * h + cB[o];
  }
}

// ---------------- pass C: apply carry, gate by silu(z), -> bf16 ----------------
__global__ void __launch_bounds__(256)
scan_c_kernel(const u16* __restrict__ g, const u16* __restrict__ xc,
              const u16* __restrict__ sz, const float* __restrict__ gbias,
              const float* __restrict__ carry, u16* __restrict__ yg) {
  const int c   = (blockIdx.x * 256 + threadIdx.x) * 2;
  const int ch  = blockIdx.y;
  const int bat = blockIdx.z;
  const float bb0 = gbias[c], bb1 = gbias[c + 1];
  const float2 h2 = *(const float2*)(carry + ((size_t)bat * NCHUNK + ch) * D_INNER + c);
  float h0 = h2.x, h1 = h2.y;
  size_t idx = ((size_t)bat * LSEQ + (size_t)ch * CHUNK) * D_INNER + c;
  for (int t = 0; t < CHUNK; ++t) {
    const ushort2 gg = *(const ushort2*)(g + idx);
    const ushort2 xx = *(const ushort2*)(xc + idx);
    const ushort2 zz = *(const ushort2*)(sz + idx);
    const float a0 = sigmoidf_(bf2f(gg.x) + bb0);
    const float a1 = sigmoidf_(bf2f(gg.y) + bb1);
    h0 = a0 * h0 + (1.0f - a0) * bf2f(xx.x);
    h1 = a1 * h1 + (1.0f - a1) * bf2f(xx.y);
    ushort2 o2;
    o2.x = f2bf(h0 * bf2f(zz.x));
    o2.y = f2bf(h1 * bf2f(zz.y));
    *(ushort2*)(yg + idx) = o2;
    idx += D_INNER;
  }
}

extern "C" void kernel_launch(void* const* d_in, const int* in_sizes, int n_in,
                              void* d_out, int out_size, void* d_ws, size_t ws_size,
                              hipStream_t stream) {
  const float* x         = (const float*)d_in[0];
  const float* norm_w    = (const float*)d_in[1];
  const float* norm_b    = (const float*)d_in[2];
  const float* in_proj_w = (const float*)d_in[3];
  const float* conv_w    = (const float*)d_in[4];
  const float* conv_b    = (const float*)d_in[5];
  const float* gate_w    = (const float*)d_in[6];
  const float* gate_b    = (const float*)d_in[7];
  const float* out_proj_w= (const float*)d_in[8];
  float* out = (float*)d_out;

  char* p = (char*)d_ws;
  u16* xn      = (u16*)p; p += (size_t)M_ROWS * D_MODEL * 2;
  u16* w_in    = (u16*)p; p += (size_t)2 * D_INNER * D_MODEL * 2;
  u16* w_gate  = (u16*)p; p += (size_t)D_INNER * D_INNER * 2;
  u16* w_out   = (u16*)p; p += (size_t)D_MODEL * D_INNER * 2;
  u16* x_inner = (u16*)p; p += (size_t)M_ROWS * D_INNER * 2;
  u16* szb     = (u16*)p; p += (size_t)M_ROWS * D_INNER * 2;
  u16* xconv   = (u16*)p; p += (size_t)M_ROWS * D_INNER * 2;
  u16* gbuf    = (u16*)p; p += (size_t)M_ROWS * D_INNER * 2;   // raw GEMM2 out
  u16* yg      = (u16*)p; p += (size_t)M_ROWS * D_INNER * 2;
  float* cA    = (float*)p; p += (size_t)BATCH * NCHUNK * D_INNER * 4;
  float* cB    = (float*)p; p += (size_t)BATCH * NCHUNK * D_INNER * 4;
  float* carry = (float*)p; p += (size_t)BATCH * NCHUNK * D_INNER * 4;
  if ((size_t)(p - (char*)d_ws) > ws_size) return;

  cast_bf16_kernel<<<dim3(2 * D_INNER * D_MODEL / 4 / 256), 256, 0, stream>>>(in_proj_w, w_in, 2 * D_INNER * D_MODEL / 4);
  cast_bf16_kernel<<<dim3(D_INNER * D_INNER / 4 / 256), 256, 0, stream>>>(gate_w, w_gate, D_INNER * D_INNER / 4);
  cast_bf16_kernel<<<dim3(D_MODEL * D_INNER / 4 / 256), 256, 0, stream>>>(out_proj_w, w_out, D_MODEL * D_INNER / 4);

  ln_kernel<<<dim3(M_ROWS), 256, 0, stream>>>(x, norm_w, norm_b, xn);

  gemm8p<0><<<dim3((M_ROWS / 256) * (2 * D_INNER / 256)), 512, 0, stream>>>(
      xn, w_in, M_ROWS, 2 * D_INNER, D_MODEL, nullptr, nullptr, x_inner, szb);

  conv_silu_kernel<<<dim3(D_INNER / 256, LSEQ / 8, BATCH), 256, 0, stream>>>(x_inner, conv_w, conv_b, xconv);

  gemm8p<1><<<dim3((M_ROWS / 256) * (D_INNER / 256)), 512, 0, stream>>>(
      xconv, w_gate, M_ROWS, D_INNER, D_INNER, nullptr, nullptr, gbuf, nullptr);

  scan_a_kernel<<<dim3(D_INNER / 512, NCHUNK, BATCH), 256, 0, stream>>>(gbuf, xconv, gate_b, cA, cB);
  scan_b_kernel<<<dim3(BATCH * D_INNER / 256), 256, 0, stream>>>(cA, cB, carry);
  scan_c_kernel<<<dim3(D_INNER / 512, NCHUNK, BATCH), 256, 0, stream>>>(gbuf, xconv, szb, gate_b, carry, yg);

  gemm128<2><<<dim3((M_ROWS / 128) * (D_MODEL / 128)), 256, 0, stream>>>(
      yg, w_out, M_ROWS, D_MODEL, D_INNER, x, out, nullptr, nullptr);
}

// Round 9
// 341.230 us; speedup vs baseline: 1.1084x; 1.1084x over previous
//
#include <hip/hip_runtime.h>
#include <cstdint>

#define D_MODEL 1024
#define D_INNER 2048
#define LSEQ    4096
#define BATCH   2
#define M_ROWS  (BATCH * LSEQ)   // 8192
#define CHUNK   128
#define NCHUNK  (LSEQ / CHUNK)   // 32

typedef unsigned short u16;
typedef __bf16 bf16x8 __attribute__((ext_vector_type(8)));
typedef float f32x4 __attribute__((ext_vector_type(4)));
typedef u16 u16x4 __attribute__((ext_vector_type(4)));

__device__ __forceinline__ u16 f2bf(float f) {
  union { float f; unsigned u; } x; x.f = f;
  unsigned u = x.u;
  unsigned r = (u + 0x7FFFu + ((u >> 16) & 1u)) >> 16;
  return (u16)r;
}
__device__ __forceinline__ float bf2f(u16 h) {
  union { unsigned u; float f; } x; x.u = ((unsigned)h) << 16;
  return x.f;
}
__device__ __forceinline__ float sigmoidf_(float v) { return 1.0f / (1.0f + expf(-v)); }
__device__ __forceinline__ float siluf_(float v)    { return v / (1.0f + expf(-v)); }

#define SBAR()   asm volatile("s_barrier" ::: "memory")
#define WAITL0() asm volatile("s_waitcnt lgkmcnt(0)" ::: "memory")

// ---------------- fused weight cast fp32 -> bf16 ----------------
__global__ void __launch_bounds__(256)
cast3_kernel(const float* __restrict__ w0, const float* __restrict__ w1,
             const float* __restrict__ w2, u16* __restrict__ o0,
             u16* __restrict__ o1, u16* __restrict__ o2) {
  const int n04 = 2 * D_INNER * D_MODEL / 4;   // 2M float4
  const int n14 = D_INNER * D_INNER / 4;       // 1M
  const int n24 = D_MODEL * D_INNER / 4;       // 512K
  int i = blockIdx.x * 256 + threadIdx.x;
  const float* src; u16* dst; int j;
  if (i < n04)            { src = w0; dst = o0; j = i; }
  else if (i < n04 + n14) { src = w1; dst = o1; j = i - n04; }
  else if (i < n04 + n14 + n24) { src = w2; dst = o2; j = i - n04 - n14; }
  else return;
  float4 v = ((const float4*)src)[j];
  u16x4 o;
  o.x = f2bf(v.x); o.y = f2bf(v.y); o.z = f2bf(v.z); o.w = f2bf(v.w);
  ((u16x4*)dst)[j] = o;
}

// ---------------- LayerNorm -> bf16 ----------------
__global__ void __launch_bounds__(256)
ln_kernel(const float* __restrict__ x, const float* __restrict__ w,
          const float* __restrict__ b, u16* __restrict__ xn) {
  const int row = blockIdx.x;
  const int t = threadIdx.x;
  const float4 v = ((const float4*)(x + (size_t)row * D_MODEL))[t];
  float s  = v.x + v.y + v.z + v.w;
  float ss = v.x * v.x + v.y * v.y + v.z * v.z + v.w * v.w;
#pragma unroll
  for (int o = 32; o > 0; o >>= 1) {
    s  += __shfl_xor(s, o);
    ss += __shfl_xor(ss, o);
  }
  __shared__ float red[8];
  const int wid = t >> 6, lane = t & 63;
  if (lane == 0) { red[wid] = s; red[4 + wid] = ss; }
  __syncthreads();
  s  = red[0] + red[1] + red[2] + red[3];
  ss = red[4] + red[5] + red[6] + red[7];
  const float mu  = s * (1.0f / D_MODEL);
  const float var = ss * (1.0f / D_MODEL) - mu * mu;
  const float rs  = rsqrtf(var + 1e-5f);
  const float4 wv = ((const float4*)w)[t];
  const float4 bv = ((const float4*)b)[t];
  u16x4 o4;
  o4.x = f2bf((v.x - mu) * rs * wv.x + bv.x);
  o4.y = f2bf((v.y - mu) * rs * wv.y + bv.y);
  o4.z = f2bf((v.z - mu) * rs * wv.z + bv.z);
  o4.w = f2bf((v.w - mu) * rs * wv.w + bv.w);
  ((u16x4*)(xn + (size_t)row * D_MODEL))[t] = o4;
}

// ======== 256xBN BK=64 8-wave REG-STAGED dbuf GEMM, C = A(MxK) * B(NxK)^T ====
// A/B for tile t+1 loaded to REGISTERS at tile-top (plain loads: compiler
// emits counted vmcnt before first use), ds_written to the idle buffer after
// the MFMA phases, one lgkmcnt(0)+s_barrier per tile. No global_load_lds.
// LDS rows 128B; 16B slot (c ^ (row&7)) both on write-source mapping and
// reads -> 0 bank conflicts (verified R2-R4/R8). Wave grid 2x4, wave tile
// 128 x BN/4, acc[8][BN/64].
#define MFMA_BF16 __builtin_amdgcn_mfma_f32_16x16x32_bf16

template<int EPI, int BN>
__global__ void __launch_bounds__(512, 2)
gemmR(const u16* __restrict__ A, const u16* __restrict__ Bm,
      int M, int N, int K,
      const float* __restrict__ ef, float* __restrict__ of,
      u16* __restrict__ ob0, u16* __restrict__ ob1) {
  constexpr int NF  = BN / 64;      // B frags per wave per kk
  constexpr int NBL = BN / 64;      // B 64-row load rounds per tile per thread
  constexpr int BBY = BN * 128;     // B tile bytes in LDS
  __shared__ __align__(1024) char lds[65536 + 2 * BBY];
  const int tid = threadIdx.x, wid = tid >> 6, lane = tid & 63;
  const int nbx = N / BN;
  const int nwg = nbx * (M >> 8);
  const int bid = blockIdx.x;
  const int cpx = nwg >> 3;                       // nwg % 8 == 0 for our shapes
  const int swzb = (bid & 7) * cpx + (bid >> 3);  // XCD-aware swizzle
  const int bx = swzb % nbx, by = swzb / nbx;
  const size_t m0 = (size_t)by << 8;
  const size_t n0 = (size_t)bx * BN;
  const int wr = wid >> 2, wc = wid & 3;
  const size_t rb = (size_t)K * 2;

  // ---- staging: round j covers rows j*64 + wid*8 + strow; thread's global
  // source chunk pre-swizzled (stchk = slot ^ row&7); LDS dest linear.
  const int strow = lane >> 3;
  const int stchk = (lane & 7) ^ strow;
  const char* gA = (const char*)A  + (m0 + (size_t)(wid * 8 + strow)) * rb + stchk * 16;
  const char* gB = (const char*)Bm + (n0 + (size_t)(wid * 8 + strow)) * rb + stchk * 16;
  const int vb = wid * 1024 + lane * 16;          // + j*8192 (+ buffer base)

  // ---- fragment reads (swizzled): byte = row*128 + ((chunk)^(row&7))<<4 ----
  const int q = lane >> 4, r15 = lane & 15;
  const int kx0 = ((q ^ (r15 & 7)) << 4);
  const int kx1 = (((4 + q) ^ (r15 & 7)) << 4);
  const int arow = (wr * 128 + r15) * 128;        // + mf*2048
  const int brow = (wc * (BN / 4) + r15) * 128;   // + nf*2048

  f32x4 acc[8][NF] = {};
  const int nk = K >> 6;
  bf16x8 rA[4], rB[NBL];

  // ---- prologue: tile 0 -> regs -> LDS buf0 ----
#pragma unroll
  for (int j = 0; j < 4; ++j)   rA[j] = *(const bf16x8*)(gA + (size_t)(j * 64) * rb);
#pragma unroll
  for (int j = 0; j < NBL; ++j) rB[j] = *(const bf16x8*)(gB + (size_t)(j * 64) * rb);
#pragma unroll
  for (int j = 0; j < 4; ++j)   *(bf16x8*)(lds + j * 8192 + vb) = rA[j];
#pragma unroll
  for (int j = 0; j < NBL; ++j) *(bf16x8*)(lds + 65536 + j * 8192 + vb) = rB[j];
  WAITL0();
  SBAR();

  size_t kb = 128;
  for (int t = 0; t < nk; ++t) {
    const int par = t & 1;
    const char* Ac = lds + par * 32768;
    const char* Bc = lds + 65536 + par * BBY;
    char* An = lds + (par ^ 1) * 32768;
    char* Bn = lds + 65536 + (par ^ 1) * BBY;
    const bool pf = (t + 1 < nk);

    // tile-top: issue t+1 loads into registers (latency hidden under MFMAs)
    if (pf) {
#pragma unroll
      for (int j = 0; j < 4; ++j)   rA[j] = *(const bf16x8*)(gA + kb + (size_t)(j * 64) * rb);
#pragma unroll
      for (int j = 0; j < NBL; ++j) rB[j] = *(const bf16x8*)(gB + kb + (size_t)(j * 64) * rb);
    }

    bf16x8 af[8], bfv[NF];
    // kk0
#pragma unroll
    for (int mf = 0; mf < 8; ++mf) af[mf] = *(const bf16x8*)(Ac + arow + mf * 2048 + kx0);
#pragma unroll
    for (int nf = 0; nf < NF; ++nf) bfv[nf] = *(const bf16x8*)(Bc + brow + nf * 2048 + kx0);
    __builtin_amdgcn_s_setprio(1);
#pragma unroll
    for (int mf = 0; mf < 8; ++mf)
#pragma unroll
      for (int nf = 0; nf < NF; ++nf)
        acc[mf][nf] = MFMA_BF16(af[mf], bfv[nf], acc[mf][nf], 0, 0, 0);
    __builtin_amdgcn_s_setprio(0);
    // kk1
#pragma unroll
    for (int mf = 0; mf < 8; ++mf) af[mf] = *(const bf16x8*)(Ac + arow + mf * 2048 + kx1);
#pragma unroll
    for (int nf = 0; nf < NF; ++nf) bfv[nf] = *(const bf16x8*)(Bc + brow + nf * 2048 + kx1);
    __builtin_amdgcn_s_setprio(1);
#pragma unroll
    for (int mf = 0; mf < 8; ++mf)
#pragma unroll
      for (int nf = 0; nf < NF; ++nf)
        acc[mf][nf] = MFMA_BF16(af[mf], bfv[nf], acc[mf][nf], 0, 0, 0);
    __builtin_amdgcn_s_setprio(0);

    // tile-end: publish staged regs to the idle buffer (compiler inserts the
    // minimal vmcnt before the first ds_write)
    if (pf) {
#pragma unroll
      for (int j = 0; j < 4; ++j)   *(bf16x8*)(An + j * 8192 + vb) = rA[j];
#pragma unroll
      for (int j = 0; j < NBL; ++j) *(bf16x8*)(Bn + j * 8192 + vb) = rB[j];
    }
    WAITL0();
    SBAR();
    kb += 128;
  }

  // ---------- epilogue (16x16 C layout: col=lane&15, row=(lane>>4)*4+r) ----
  const int c0 = lane & 15;
  const int r0 = (lane >> 4) << 2;
  const bool isz = (EPI == 0) && (n0 >= (size_t)D_INNER);
#pragma unroll
  for (int mf = 0; mf < 8; ++mf) {
#pragma unroll
    for (int nf = 0; nf < NF; ++nf) {
#pragma unroll
      for (int rg = 0; rg < 4; ++rg) {
        const size_t row = m0 + (size_t)(wr * 128 + mf * 16 + r0 + rg);
        const size_t col = n0 + (size_t)(wc * (BN / 4) + nf * 16 + c0);
        const float v = acc[mf][nf][rg];
        if (EPI == 0) {
          if (!isz) ob0[row * D_INNER + col] = f2bf(v);
          else      ob1[row * D_INNER + (col - D_INNER)] = f2bf(siluf_(v));
        } else if (EPI == 1) {
          ob0[row * (size_t)N + col] = f2bf(v);
        } else {
          of[row * (size_t)N + col] = v + ef[row * (size_t)N + col];
        }
      }
    }
  }
}

// ---------------- causal depthwise conv (K=4) + SiLU ----------------
__global__ void __launch_bounds__(256)
conv_silu_kernel(const u16* __restrict__ xin, const float* __restrict__ cw,
                 const float* __restrict__ cb, u16* __restrict__ xc) {
  const int c   = blockIdx.x * 256 + threadIdx.x;
  const int l0  = blockIdx.y * 8;
  const int bat = blockIdx.z;
  const size_t base = ((size_t)bat * LSEQ) * D_INNER + c;
  const float w0 = cw[c * 4 + 0], w1 = cw[c * 4 + 1], w2 = cw[c * 4 + 2], w3 = cw[c * 4 + 3];
  const float bb = cb[c];
  float v[11];
#pragma unroll
  for (int i = 0; i < 11; ++i) {
    const int l = l0 - 3 + i;
    v[i] = (l >= 0) ? bf2f(xin[base + (size_t)l * D_INNER]) : 0.0f;
  }
#pragma unroll
  for (int r = 0; r < 8; ++r) {
    const float acc = bb + w0 * v[r] + w1 * v[r + 1] + w2 * v[r + 2] + w3 * v[r + 3];
    xc[base + (size_t)(l0 + r) * D_INNER] = f2bf(siluf_(acc));
  }
}

// ---------------- chunked scan: pass A (2 channels/thread) ----------------
__global__ void __launch_bounds__(256)
scan_a_kernel(const u16* __restrict__ g, const u16* __restrict__ xc,
              const float* __restrict__ gbias,
              float* __restrict__ cA, float* __restrict__ cB) {
  const int c   = (blockIdx.x * 256 + threadIdx.x) * 2;
  const int ch  = blockIdx.y;
  const int bat = blockIdx.z;
  const float bb0 = gbias[c], bb1 = gbias[c + 1];
  size_t idx = ((size_t)bat * LSEQ + (size_t)ch * CHUNK) * D_INNER + c;
  float pA0 = 1.0f, hB0 = 0.0f, pA1 = 1.0f, hB1 = 0.0f;
  for (int t = 0; t < CHUNK; ++t) {
    const ushort2 gg = *(const ushort2*)(g + idx);
    const ushort2 xx = *(const ushort2*)(xc + idx);
    const float a0 = sigmoidf_(bf2f(gg.x) + bb0);
    const float a1 = sigmoidf_(bf2f(gg.y) + bb1);
    pA0 *= a0; hB0 = a0 * hB0 + (1.0f - a0) * bf2f(xx.x);
    pA1 *= a1; hB1 = a1 * hB1 + (1.0f - a1) * bf2f(xx.y);
    idx += D_INNER;
  }
  const size_t o = ((size_t)bat * NCHUNK + ch) * D_INNER + c;
  *(float2*)(cA + o) = make_float2(pA0, pA1);
  *(float2*)(cB + o) = make_float2(hB0, hB1);
}

// ---------------- pass B: serial scan over chunk summaries ----------------
__global__ void __launch_bounds__(256)
scan_b_kernel(const float* __restrict__ cA, const float* __restrict__ cB,
              float* __restrict__ carry) {
  const int tid = blockIdx.x * 256 + threadIdx.x;  // BATCH*D_INNER = 4096
  const int bat = tid >> 11;
  const int c   = tid & (D_INNER - 1);
  float h = 0.0f;
  const size_t base = (size_t)bat * NCHUNK * D_INNER + c;
  for (int i = 0; i < NCHUNK; ++i) {
    const size_t o = base + (size_t)i * D_INNER;
    carry[o] = h;
    h = cA[o] * h + cB[o];
  }
}

// ---------------- pass C: apply carry, gate by silu(z), -> bf16 ----------------
__global__ void __launch_bounds__(256)
scan_c_kernel(const u16* __restrict__ g, const u16* __restrict__ xc,
              const u16* __restrict__ sz, const float* __restrict__ gbias,
              const float* __restrict__ carry, u16* __restrict__ yg) {
  const int c   = (blockIdx.x * 256 + threadIdx.x) * 2;
  const int ch  = blockIdx.y;
  const int bat = blockIdx.z;
  const float bb0 = gbias[c], bb1 = gbias[c + 1];
  const float2 h2 = *(const float2*)(carry + ((size_t)bat * NCHUNK + ch) * D_INNER + c);
  float h0 = h2.x, h1 = h2.y;
  size_t idx = ((size_t)bat * LSEQ + (size_t)ch * CHUNK) * D_INNER + c;
  for (int t = 0; t < CHUNK; ++t) {
    const ushort2 gg = *(const ushort2*)(g + idx);
    const ushort2 xx = *(const ushort2*)(xc + idx);
    const ushort2 zz = *(const ushort2*)(sz + idx);
    const float a0 = sigmoidf_(bf2f(gg.x) + bb0);
    const float a1 = sigmoidf_(bf2f(gg.y) + bb1);
    h0 = a0 * h0 + (1.0f - a0) * bf2f(xx.x);
    h1 = a1 * h1 + (1.0f - a1) * bf2f(xx.y);
    ushort2 o2;
    o2.x = f2bf(h0 * bf2f(zz.x));
    o2.y = f2bf(h1 * bf2f(zz.y));
    *(ushort2*)(yg + idx) = o2;
    idx += D_INNER;
  }
}

extern "C" void kernel_launch(void* const* d_in, const int* in_sizes, int n_in,
                              void* d_out, int out_size, void* d_ws, size_t ws_size,
                              hipStream_t stream) {
  const float* x         = (const float*)d_in[0];
  const float* norm_w    = (const float*)d_in[1];
  const float* norm_b    = (const float*)d_in[2];
  const float* in_proj_w = (const float*)d_in[3];
  const float* conv_w    = (const float*)d_in[4];
  const float* conv_b    = (const float*)d_in[5];
  const float* gate_w    = (const float*)d_in[6];
  const float* gate_b    = (const float*)d_in[7];
  const float* out_proj_w= (const float*)d_in[8];
  float* out = (float*)d_out;

  char* p = (char*)d_ws;
  u16* xn      = (u16*)p; p += (size_t)M_ROWS * D_MODEL * 2;
  u16* w_in    = (u16*)p; p += (size_t)2 * D_INNER * D_MODEL * 2;
  u16* w_gate  = (u16*)p; p += (size_t)D_INNER * D_INNER * 2;
  u16* w_out   = (u16*)p; p += (size_t)D_MODEL * D_INNER * 2;
  u16* x_inner = (u16*)p; p += (size_t)M_ROWS * D_INNER * 2;
  u16* szb     = (u16*)p; p += (size_t)M_ROWS * D_INNER * 2;
  u16* xconv   = (u16*)p; p += (size_t)M_ROWS * D_INNER * 2;
  u16* gbuf    = (u16*)p; p += (size_t)M_ROWS * D_INNER * 2;   // raw GEMM2 out
  u16* yg      = (u16*)p; p += (size_t)M_ROWS * D_INNER * 2;
  float* cA    = (float*)p; p += (size_t)BATCH * NCHUNK * D_INNER * 4;
  float* cB    = (float*)p; p += (size_t)BATCH * NCHUNK * D_INNER * 4;
  float* carry = (float*)p; p += (size_t)BATCH * NCHUNK * D_INNER * 4;
  if ((size_t)(p - (char*)d_ws) > ws_size) return;

  const int ncast4 = (2 * D_INNER * D_MODEL + D_INNER * D_INNER + D_MODEL * D_INNER) / 4;
  cast3_kernel<<<dim3((ncast4 + 255) / 256), 256, 0, stream>>>(
      in_proj_w, gate_w, out_proj_w, w_in, w_gate, w_out);

  ln_kernel<<<dim3(M_ROWS), 256, 0, stream>>>(x, norm_w, norm_b, xn);

  gemmR<0, 256><<<dim3((M_ROWS / 256) * (2 * D_INNER / 256)), 512, 0, stream>>>(
      xn, w_in, M_ROWS, 2 * D_INNER, D_MODEL, nullptr, nullptr, x_inner, szb);

  conv_silu_kernel<<<dim3(D_INNER / 256, LSEQ / 8, BATCH), 256, 0, stream>>>(x_inner, conv_w, conv_b, xconv);

  gemmR<1, 256><<<dim3((M_ROWS / 256) * (D_INNER / 256)), 512, 0, stream>>>(
      xconv, w_gate, M_ROWS, D_INNER, D_INNER, nullptr, nullptr, gbuf, nullptr);

  scan_a_kernel<<<dim3(D_INNER / 512, NCHUNK, BATCH), 256, 0, stream>>>(gbuf, xconv, gate_b, cA, cB);
  scan_b_kernel<<<dim3(BATCH * D_INNER / 256), 256, 0, stream>>>(cA, cB, carry);
  scan_c_kernel<<<dim3(D_INNER / 512, NCHUNK, BATCH), 256, 0, stream>>>(gbuf, xconv, szb, gate_b, carry, yg);

  gemmR<2, 128><<<dim3((M_ROWS / 256) * (D_MODEL / 128)), 512, 0, stream>>>(
      yg, w_out, M_ROWS, D_MODEL, D_INNER, x, out, nullptr, nullptr);
}

// Round 10
// 323.323 us; speedup vs baseline: 1.1698x; 1.0554x over previous
//
#include <hip/hip_runtime.h>
#include <cstdint>

#define D_MODEL 1024
#define D_INNER 2048
#define LSEQ    4096
#define BATCH   2
#define M_ROWS  (BATCH * LSEQ)   // 8192
#define CHUNK   128
#define NCHUNK  (LSEQ / CHUNK)   // 32

typedef unsigned short u16;
typedef __bf16 bf16x8 __attribute__((ext_vector_type(8)));
typedef float f32x4 __attribute__((ext_vector_type(4)));
typedef u16 u16x4 __attribute__((ext_vector_type(4)));

__device__ __forceinline__ u16 f2bf(float f) {
  union { float f; unsigned u; } x; x.f = f;
  unsigned u = x.u;
  unsigned r = (u + 0x7FFFu + ((u >> 16) & 1u)) >> 16;
  return (u16)r;
}
__device__ __forceinline__ float bf2f(u16 h) {
  union { unsigned u; float f; } x; x.u = ((unsigned)h) << 16;
  return x.f;
}
__device__ __forceinline__ float sigmoidf_(float v) { return 1.0f / (1.0f + expf(-v)); }
__device__ __forceinline__ float siluf_(float v)    { return v / (1.0f + expf(-v)); }

__device__ __forceinline__ void gl_lds16(const void* g, void* l) {
  __builtin_amdgcn_global_load_lds(
      (const __attribute__((address_space(1))) void*)g,
      (__attribute__((address_space(3))) void*)l, 16, 0, 0);
}

#define SBAR()   asm volatile("s_barrier" ::: "memory")
#define WAITV0() asm volatile("s_waitcnt vmcnt(0)" ::: "memory")
#define SGB()    __builtin_amdgcn_sched_barrier(0)

// ---------------- fused weight cast fp32 -> bf16 ----------------
__global__ void __launch_bounds__(256)
cast3_kernel(const float* __restrict__ w0, const float* __restrict__ w1,
             const float* __restrict__ w2, u16* __restrict__ o0,
             u16* __restrict__ o1, u16* __restrict__ o2) {
  const int n04 = 2 * D_INNER * D_MODEL / 4;
  const int n14 = D_INNER * D_INNER / 4;
  const int n24 = D_MODEL * D_INNER / 4;
  int i = blockIdx.x * 256 + threadIdx.x;
  const float* src; u16* dst; int j;
  if (i < n04)            { src = w0; dst = o0; j = i; }
  else if (i < n04 + n14) { src = w1; dst = o1; j = i - n04; }
  else if (i < n04 + n14 + n24) { src = w2; dst = o2; j = i - n04 - n14; }
  else return;
  float4 v = ((const float4*)src)[j];
  u16x4 o;
  o.x = f2bf(v.x); o.y = f2bf(v.y); o.z = f2bf(v.z); o.w = f2bf(v.w);
  ((u16x4*)dst)[j] = o;
}

// ---------------- LayerNorm -> bf16 ----------------
__global__ void __launch_bounds__(256)
ln_kernel(const float* __restrict__ x, const float* __restrict__ w,
          const float* __restrict__ b, u16* __restrict__ xn) {
  const int row = blockIdx.x;
  const int t = threadIdx.x;
  const float4 v = ((const float4*)(x + (size_t)row * D_MODEL))[t];
  float s  = v.x + v.y + v.z + v.w;
  float ss = v.x * v.x + v.y * v.y + v.z * v.z + v.w * v.w;
#pragma unroll
  for (int o = 32; o > 0; o >>= 1) {
    s  += __shfl_xor(s, o);
    ss += __shfl_xor(ss, o);
  }
  __shared__ float red[8];
  const int wid = t >> 6, lane = t & 63;
  if (lane == 0) { red[wid] = s; red[4 + wid] = ss; }
  __syncthreads();
  s  = red[0] + red[1] + red[2] + red[3];
  ss = red[4] + red[5] + red[6] + red[7];
  const float mu  = s * (1.0f / D_MODEL);
  const float var = ss * (1.0f / D_MODEL) - mu * mu;
  const float rs  = rsqrtf(var + 1e-5f);
  const float4 wv = ((const float4*)w)[t];
  const float4 bv = ((const float4*)b)[t];
  u16x4 o4;
  o4.x = f2bf((v.x - mu) * rs * wv.x + bv.x);
  o4.y = f2bf((v.y - mu) * rs * wv.y + bv.y);
  o4.z = f2bf((v.z - mu) * rs * wv.z + bv.z);
  o4.w = f2bf((v.w - mu) * rs * wv.w + bv.w);
  ((u16x4*)(xn + (size_t)row * D_MODEL))[t] = o4;
}

// ======== 256xBN BK=64 8-wave PIPELINED GEMM, C = A(MxK) * B(NxK)^T ========
// Key mechanism (R10): every phase issues the ds_reads for the NEXT phase's
// MFMA, so the LDS pipe services reads WHILE the matrix pipe runs the current
// quadrant. No runtime barrier between phases (sched_barrier(0) pins program
// order; waves free-run and drift, mixing pipes). One vmcnt(0)+s_barrier per
// K-tile, placed AFTER the last MFMA consuming the old buffer (rigorous WAR)
// and draining loads issued 2-3 phases earlier. Stages: PhA=A(t+1), PhB=B(t+1)
// via global_load_lds. Swizzle: global chunk (c ^ row&7) -> slot c; reads XOR
// the same (0 conflicts, verified R2-R9). Wave grid 2x4, wave tile 128 x BN/4.
#define MFMA_BF16 __builtin_amdgcn_mfma_f32_16x16x32_bf16

template<int EPI, int BN>
__global__ void __launch_bounds__(512, 2)
gemmP(const u16* __restrict__ A, const u16* __restrict__ Bm,
      int M, int N, int K,
      const float* __restrict__ ef, float* __restrict__ of,
      u16* __restrict__ ob0, u16* __restrict__ ob1) {
  constexpr int NF  = BN / 64;        // B frags per wave per kk
  constexpr int NF2 = NF / 2;         // frags per n-half
  constexpr int BBY = BN * 128;       // B tile bytes
  constexpr int BH  = BN / 128;       // B halves
  __shared__ __align__(1024) char lds[65536 + 2 * BBY];
  const int tid = threadIdx.x, wid = tid >> 6, lane = tid & 63;
  const int nbx = N / BN;
  const int nwg = nbx * (M >> 8);
  const int bid = blockIdx.x;
  const int cpx = nwg >> 3;                       // nwg % 8 == 0 for our shapes
  const int swzb = (bid & 7) * cpx + (bid >> 3);  // XCD-aware swizzle
  const int bx = swzb % nbx, by = swzb / nbx;
  const size_t m0 = (size_t)by << 8;
  const size_t n0 = (size_t)bx * BN;
  const int wr = wid >> 2, wc = wid & 3;
  const size_t rb = (size_t)K * 2;

  // ---- staging: thread covers (row wid*8 + lane>>3, chunk lane&7); global
  // source chunk pre-swizzled by row&7; LDS dest linear (HW: base + lane*16).
  const int strow = lane >> 3;
  const int stchk = (lane & 7) ^ strow;
  const char* gA = (const char*)A  + (m0 + (size_t)(wid * 8 + strow)) * rb + stchk * 16;
  const char* gB = (const char*)Bm + (n0 + (size_t)(wid * 8 + strow)) * rb + stchk * 16;
  const int sdw = wid * 1024;

  auto ST_A = [&](int t) {                       // 4 gl_lds: rows 0..255
    char* d = lds + (t & 1) * 32768 + sdw;
    const char* s = gA + (size_t)t * 128;
#pragma unroll
    for (int h = 0; h < 2; ++h) {
      gl_lds16(s + (size_t)(h * 128) * rb,      d + h * 16384);
      gl_lds16(s + (size_t)(h * 128 + 64) * rb, d + h * 16384 + 8192);
    }
  };
  auto ST_B = [&](int t) {                       // 2*BH gl_lds
    char* d = lds + 65536 + (t & 1) * BBY + sdw;
    const char* s = gB + (size_t)t * 128;
#pragma unroll
    for (int h = 0; h < BH; ++h) {
      gl_lds16(s + (size_t)(h * 128) * rb,      d + h * 16384);
      gl_lds16(s + (size_t)(h * 128 + 64) * rb, d + h * 16384 + 8192);
    }
  };

  // ---- fragment read addressing (swizzled) ----
  const int q = lane >> 4, r15 = lane & 15;
  const int kx0 = ((q ^ (r15 & 7)) << 4);
  const int kx1 = (((4 + q) ^ (r15 & 7)) << 4);
  const int arow = r15 * 128;                    // + mf*2048, base + wr*16384
  const int bwoff = (BN == 256) ? ((wc >> 1) * 16384) : 0;
  const int brow  = (BN == 256) ? (((wc & 1) * 64 + r15) * 128)
                                : ((wc * 32 + r15) * 128);

  bf16x8 af0[8], af1[8], b01[NF2], b23[NF2], c01[NF2], c23[NF2];
  f32x4 acc[8][NF] = {};

#define RDA(dst, kx, base) _Pragma("unroll") \
  for (int mf = 0; mf < 8; ++mf) dst[mf] = *(const bf16x8*)((base) + mf * 2048 + arow + (kx));
#define RDB(dst, kx, base, nf0) _Pragma("unroll") \
  for (int nf = 0; nf < NF2; ++nf) dst[nf] = *(const bf16x8*)((base) + (nf0 + nf) * 2048 + brow + (kx));
#define MM(afr, bfr, nf0) do { __builtin_amdgcn_s_setprio(1); _Pragma("unroll") \
  for (int mf = 0; mf < 8; ++mf) _Pragma("unroll") \
    for (int nf = 0; nf < NF2; ++nf) \
      acc[mf][nf0 + nf] = MFMA_BF16(afr[mf], bfr[nf], acc[mf][nf0 + nf], 0, 0, 0); \
  __builtin_amdgcn_s_setprio(0); } while (0)

  const int nk = K >> 6;

  // ---- prologue: stage T0; prove; pre-read af0(kk0), b01(kk0) ----
  ST_A(0); ST_B(0);
  WAITV0();
  SBAR();
  {
    const char* Ab = lds + wr * 16384;
    const char* Bb = lds + 65536 + bwoff;
    RDA(af0, kx0, Ab);
    RDB(b01, kx0, Bb, 0);
  }

  for (int t = 0; t < nk; ++t) {
    const int p = t & 1;
    const char* Ab = lds + p * 32768 + wr * 16384;
    const char* Bb = lds + 65536 + p * BBY + bwoff;
    const char* An = lds + (p ^ 1) * 32768 + wr * 16384;
    const char* Bn = lds + 65536 + (p ^ 1) * BBY + bwoff;
    const bool pf = (t + 1 < nk);

    // PhA: stage A(t+1); read b23(kk0); MFMA kk0-LO
    if (pf) ST_A(t + 1);
    RDB(b23, kx0, Bb, NF2);
    SGB();
    MM(af0, b01, 0);
    SGB();

    // PhB: stage B(t+1); read af1(kk1)+c01(kk1); MFMA kk0-HI
    if (pf) ST_B(t + 1);
    RDA(af1, kx1, Ab);
    RDB(c01, kx1, Bb, 0);
    SGB();
    MM(af0, b23, NF2);
    SGB();

    // PhC: read c23(kk1); MFMA kk1-LO
    RDB(c23, kx1, Bb, NF2);
    SGB();
    MM(af1, c01, 0);
    SGB();

    // PhD: MFMA kk1-HI; then prove t+1 + barrier; pre-read next kk0 operands
    MM(af1, c23, NF2);
    if (pf) {
      WAITV0();        // t+1 stages issued 2-3 phases ago (L2-warm)
      SBAR();          // publishes t+1; all old-buffer reads consumed above
      RDA(af0, kx0, An);
      RDB(b01, kx0, Bn, 0);
    }
  }

#undef RDA
#undef RDB
#undef MM

  // ---------- epilogue (16x16 C layout: col=lane&15, row=(lane>>4)*4+r) ----
  const int c0 = lane & 15;
  const int r0 = (lane >> 4) << 2;
  const bool isz = (EPI == 0) && (n0 >= (size_t)D_INNER);
#pragma unroll
  for (int mf = 0; mf < 8; ++mf) {
#pragma unroll
    for (int nf = 0; nf < NF; ++nf) {
#pragma unroll
      for (int rg = 0; rg < 4; ++rg) {
        const size_t row = m0 + (size_t)(wr * 128 + mf * 16 + r0 + rg);
        const size_t col = n0 + (size_t)(wc * (BN / 4) + nf * 16 + c0);
        const float v = acc[mf][nf][rg];
        if (EPI == 0) {
          if (!isz) ob0[row * D_INNER + col] = f2bf(v);
          else      ob1[row * D_INNER + (col - D_INNER)] = f2bf(siluf_(v));
        } else if (EPI == 1) {
          ob0[row * (size_t)N + col] = f2bf(v);
        } else {
          of[row * (size_t)N + col] = v + ef[row * (size_t)N + col];
        }
      }
    }
  }
}

// ---------------- causal depthwise conv (K=4) + SiLU ----------------
__global__ void __launch_bounds__(256)
conv_silu_kernel(const u16* __restrict__ xin, const float* __restrict__ cw,
                 const float* __restrict__ cb, u16* __restrict__ xc) {
  const int c   = blockIdx.x * 256 + threadIdx.x;
  const int l0  = blockIdx.y * 8;
  const int bat = blockIdx.z;
  const size_t base = ((size_t)bat * LSEQ) * D_INNER + c;
  const float w0 = cw[c * 4 + 0], w1 = cw[c * 4 + 1], w2 = cw[c * 4 + 2], w3 = cw[c * 4 + 3];
  const float bb = cb[c];
  float v[11];
#pragma unroll
  for (int i = 0; i < 11; ++i) {
    const int l = l0 - 3 + i;
    v[i] = (l >= 0) ? bf2f(xin[base + (size_t)l * D_INNER]) : 0.0f;
  }
#pragma unroll
  for (int r = 0; r < 8; ++r) {
    const float acc = bb + w0 * v[r] + w1 * v[r + 1] + w2 * v[r + 2] + w3 * v[r + 3];
    xc[base + (size_t)(l0 + r) * D_INNER] = f2bf(siluf_(acc));
  }
}

// ---------------- chunked scan: pass A (2 channels/thread) ----------------
__global__ void __launch_bounds__(256)
scan_a_kernel(const u16* __restrict__ g, const u16* __restrict__ xc,
              const float* __restrict__ gbias,
              float* __restrict__ cA, float* __restrict__ cB) {
  const int c   = (blockIdx.x * 256 + threadIdx.x) * 2;
  const int ch  = blockIdx.y;
  const int bat = blockIdx.z;
  const float bb0 = gbias[c], bb1 = gbias[c + 1];
  size_t idx = ((size_t)bat * LSEQ + (size_t)ch * CHUNK) * D_INNER + c;
  float pA0 = 1.0f, hB0 = 0.0f, pA1 = 1.0f, hB1 = 0.0f;
  for (int t = 0; t < CHUNK; ++t) {
    const ushort2 gg = *(const ushort2*)(g + idx);
    const ushort2 xx = *(const ushort2*)(xc + idx);
    const float a0 = sigmoidf_(bf2f(gg.x) + bb0);
    const float a1 = sigmoidf_(bf2f(gg.y) + bb1);
    pA0 *= a0; hB0 = a0 * hB0 + (1.0f - a0) * bf2f(xx.x);
    pA1 *= a1; hB1 = a1 * hB1 + (1.0f - a1) * bf2f(xx.y);
    idx += D_INNER;
  }
  const size_t o = ((size_t)bat * NCHUNK + ch) * D_INNER + c;
  *(float2*)(cA + o) = make_float2(pA0, pA1);
  *(float2*)(cB + o) = make_float2(hB0, hB1);
}

// ---------------- pass B: serial scan over chunk summaries ----------------
__global__ void __launch_bounds__(256)
scan_b_kernel(const float* __restrict__ cA, const float* __restrict__ cB,
              float* __restrict__ carry) {
  const int tid = blockIdx.x * 256 + threadIdx.x;  // BATCH*D_INNER = 4096
  const int bat = tid >> 11;
  const int c   = tid & (D_INNER - 1);
  float h = 0.0f;
  const size_t base = (size_t)bat * NCHUNK * D_INNER + c;
  for (int i = 0; i < NCHUNK; ++i) {
    const size_t o = base + (size_t)i * D_INNER;
    carry[o] = h;
    h = cA[o] * h + cB[o];
  }
}

// ---------------- pass C: apply carry, gate by silu(z), -> bf16 ----------------
__global__ void __launch_bounds__(256)
scan_c_kernel(const u16* __restrict__ g, const u16* __restrict__ xc,
              const u16* __restrict__ sz, const float* __restrict__ gbias,
              const float* __restrict__ carry, u16* __restrict__ yg) {
  const int c   = (blockIdx.x * 256 + threadIdx.x) * 2;
  const int ch  = blockIdx.y;
  const int bat = blockIdx.z;
  const float bb0 = gbias[c], bb1 = gbias[c + 1];
  const float2 h2 = *(const float2*)(carry + ((size_t)bat * NCHUNK + ch) * D_INNER + c);
  float h0 = h2.x, h1 = h2.y;
  size_t idx = ((size_t)bat * LSEQ + (size_t)ch * CHUNK) * D_INNER + c;
  for (int t = 0; t < CHUNK; ++t) {
    const ushort2 gg = *(const ushort2*)(g + idx);
    const ushort2 xx = *(const ushort2*)(xc + idx);
    const ushort2 zz = *(const ushort2*)(sz + idx);
    const float a0 = sigmoidf_(bf2f(gg.x) + bb0);
    const float a1 = sigmoidf_(bf2f(gg.y) + bb1);
    h0 = a0 * h0 + (1.0f - a0) * bf2f(xx.x);
    h1 = a1 * h1 + (1.0f - a1) * bf2f(xx.y);
    ushort2 o2;
    o2.x = f2bf(h0 * bf2f(zz.x));
    o2.y = f2bf(h1 * bf2f(zz.y));
    *(ushort2*)(yg + idx) = o2;
    idx += D_INNER;
  }
}

extern "C" void kernel_launch(void* const* d_in, const int* in_sizes, int n_in,
                              void* d_out, int out_size, void* d_ws, size_t ws_size,
                              hipStream_t stream) {
  const float* x         = (const float*)d_in[0];
  const float* norm_w    = (const float*)d_in[1];
  const float* norm_b    = (const float*)d_in[2];
  const float* in_proj_w = (const float*)d_in[3];
  const float* conv_w    = (const float*)d_in[4];
  const float* conv_b    = (const float*)d_in[5];
  const float* gate_w    = (const float*)d_in[6];
  const float* gate_b    = (const float*)d_in[7];
  const float* out_proj_w= (const float*)d_in[8];
  float* out = (float*)d_out;

  char* p = (char*)d_ws;
  u16* xn      = (u16*)p; p += (size_t)M_ROWS * D_MODEL * 2;
  u16* w_in    = (u16*)p; p += (size_t)2 * D_INNER * D_MODEL * 2;
  u16* w_gate  = (u16*)p; p += (size_t)D_INNER * D_INNER * 2;
  u16* w_out   = (u16*)p; p += (size_t)D_MODEL * D_INNER * 2;
  u16* x_inner = (u16*)p; p += (size_t)M_ROWS * D_INNER * 2;
  u16* szb     = (u16*)p; p += (size_t)M_ROWS * D_INNER * 2;
  u16* xconv   = (u16*)p; p += (size_t)M_ROWS * D_INNER * 2;
  u16* gbuf    = (u16*)p; p += (size_t)M_ROWS * D_INNER * 2;   // raw GEMM2 out
  u16* yg      = (u16*)p; p += (size_t)M_ROWS * D_INNER * 2;
  float* cA    = (float*)p; p += (size_t)BATCH * NCHUNK * D_INNER * 4;
  float* cB    = (float*)p; p += (size_t)BATCH * NCHUNK * D_INNER * 4;
  float* carry = (float*)p; p += (size_t)BATCH * NCHUNK * D_INNER * 4;
  if ((size_t)(p - (char*)d_ws) > ws_size) return;

  const int ncast4 = (2 * D_INNER * D_MODEL + D_INNER * D_INNER + D_MODEL * D_INNER) / 4;
  cast3_kernel<<<dim3((ncast4 + 255) / 256), 256, 0, stream>>>(
      in_proj_w, gate_w, out_proj_w, w_in, w_gate, w_out);

  ln_kernel<<<dim3(M_ROWS), 256, 0, stream>>>(x, norm_w, norm_b, xn);

  gemmP<0, 256><<<dim3((M_ROWS / 256) * (2 * D_INNER / 256)), 512, 0, stream>>>(
      xn, w_in, M_ROWS, 2 * D_INNER, D_MODEL, nullptr, nullptr, x_inner, szb);

  conv_silu_kernel<<<dim3(D_INNER / 256, LSEQ / 8, BATCH), 256, 0, stream>>>(x_inner, conv_w, conv_b, xconv);

  gemmP<1, 256><<<dim3((M_ROWS / 256) * (D_INNER / 256)), 512, 0, stream>>>(
      xconv, w_gate, M_ROWS, D_INNER, D_INNER, nullptr, nullptr, gbuf, nullptr);

  scan_a_kernel<<<dim3(D_INNER / 512, NCHUNK, BATCH), 256, 0, stream>>>(gbuf, xconv, gate_b, cA, cB);
  scan_b_kernel<<<dim3(BATCH * D_INNER / 256), 256, 0, stream>>>(cA, cB, carry);
  scan_c_kernel<<<dim3(D_INNER / 512, NCHUNK, BATCH), 256, 0, stream>>>(gbuf, xconv, szb, gate_b, carry, yg);

  gemmP<2, 128><<<dim3((M_ROWS / 256) * (D_MODEL / 128)), 512, 0, stream>>>(
      yg, w_out, M_ROWS, D_MODEL, D_INNER, x, out, nullptr, nullptr);
}